// Round 5
// baseline (17215.627 us; speedup 1.0000x reference)
//
#include <hip/hip_runtime.h>
#include <stdint.h>

// ---------------- problem constants ----------------
#define B_     1024
#define F_     512
#define H_     1024
#define S_     8
#define BOX_   12
#define MAXB_  64
#define MAXSY_ 64
#define L_     126
#define STK_   3

typedef unsigned short u16;
typedef unsigned int   u32;
typedef __attribute__((ext_vector_type(8))) short sh8;   // 8 bf16 (4 VGPRs)
typedef __attribute__((ext_vector_type(4))) float f4;    // MFMA accumulator

#define MFMA16(a,b,c) __builtin_amdgcn_mfma_f32_16x16x32_bf16((a),(b),(c),0,0,0)

// ---------------- ws layout (bytes) ----------------
constexpr size_t PL_HF = (size_t)H_ * F_ * 2;      // 1 MB  (Wd, Wsd planes)
constexpr size_t PL_FH = (size_t)F_ * H_ * 2;      // 1 MB  (Wl, Wr, Wsf planes)
constexpr size_t PL_SS = 16384;                    // S*H*2
constexpr size_t PL_BX = 16384;                    // BOX*F*2=12288, padded
constexpr size_t O_WdHi  = 4096;
constexpr size_t O_WdLo  = O_WdHi  + PL_HF;
constexpr size_t O_WsdHi = O_WdLo  + PL_HF;
constexpr size_t O_WsdLo = O_WsdHi + PL_HF;
constexpr size_t O_WlHi  = O_WsdLo + PL_HF;
constexpr size_t O_WlLo  = O_WlHi  + PL_FH;
constexpr size_t O_WrHi  = O_WlLo  + PL_FH;
constexpr size_t O_WrLo  = O_WrHi  + PL_FH;
constexpr size_t O_WsfHi = O_WrLo  + PL_FH;
constexpr size_t O_WsfLo = O_WsfHi + PL_FH;
constexpr size_t O_WssHi = O_WsfLo + PL_FH;
constexpr size_t O_WssLo = O_WssHi + PL_SS;
constexpr size_t O_WbxHi = O_WssLo + PL_SS;
constexpr size_t O_WbxLo = O_WbxHi + PL_BX;
constexpr size_t SZ_STK  = (size_t)B_ * STK_ * F_ * 2;   // 3 MB per plane
constexpr size_t O_SHi   = O_WbxLo + PL_BX;
constexpr size_t O_SLo   = O_SHi   + SZ_STK;
constexpr size_t SZ_H    = (size_t)B_ * H_ * 2;          // 2 MB per plane
constexpr size_t O_HAHi  = O_SLo   + SZ_STK;
constexpr size_t O_HALo  = O_HAHi  + SZ_H;
constexpr size_t O_HSHi  = O_HALo  + SZ_H;
constexpr size_t O_HSLo  = O_HSHi  + SZ_H;
constexpr size_t WS_NEED = O_HSLo  + SZ_H;               // ~24.1 MB

// ---------------- numeric helpers ----------------
__device__ __forceinline__ float bf2float(u16 h) {
    union { u32 u; float f; } v; v.u = ((u32)h) << 16; return v.f;
}
__device__ __forceinline__ u16 bfhi_of(float f) {           // RNE fp32->bf16
    union { float f; u32 u; } v; v.f = f;
    u32 u = v.u;
    return (u16)((u + 0x7fffu + ((u >> 16) & 1u)) >> 16);
}
__device__ __forceinline__ void split2(float x, u16& hi, u16& lo) {
    hi = bfhi_of(x);
    lo = bfhi_of(x - bf2float(hi));
}

// ---------------- prep: split weights + input stacks to bf16 hi/lo ----------------
__device__ void split_range(const float* __restrict__ s, u16* hi, u16* lo,
                            int n, int t0, int stride) {
    for (int i = t0; i < n; i += stride) {
        float v = s[i];
        u16 h = bfhi_of(v);
        hi[i] = h;
        lo[i] = bfhi_of(v - bf2float(h));
    }
}

__global__ void grass_prep(const float* __restrict__ X,
                           const float* __restrict__ Wd, const float* __restrict__ Wl,
                           const float* __restrict__ Wr, const float* __restrict__ Wsd,
                           const float* __restrict__ Wsf, const float* __restrict__ Wss,
                           const float* __restrict__ Wbox, char* __restrict__ ws)
{
    const int t0 = blockIdx.x * blockDim.x + threadIdx.x;
    const int st = gridDim.x * blockDim.x;
    split_range(Wd,  (u16*)(ws + O_WdHi),  (u16*)(ws + O_WdLo),  H_ * F_, t0, st);
    split_range(Wsd, (u16*)(ws + O_WsdHi), (u16*)(ws + O_WsdLo), H_ * F_, t0, st);
    split_range(Wl,  (u16*)(ws + O_WlHi),  (u16*)(ws + O_WlLo),  F_ * H_, t0, st);
    split_range(Wr,  (u16*)(ws + O_WrHi),  (u16*)(ws + O_WrLo),  F_ * H_, t0, st);
    split_range(Wsf, (u16*)(ws + O_WsfHi), (u16*)(ws + O_WsfLo), F_ * H_, t0, st);
    split_range(Wss, (u16*)(ws + O_WssHi), (u16*)(ws + O_WssLo), S_ * H_, t0, st);
    split_range(Wbox,(u16*)(ws + O_WbxHi), (u16*)(ws + O_WbxLo), BOX_ * F_, t0, st);
    u16* SHi = (u16*)(ws + O_SHi);
    u16* SLo = (u16*)(ws + O_SLo);
    for (int i = t0; i < B_ * F_; i += st) {
        int e = i >> 9, k = i & (F_ - 1);
        float v = X[i];
        u16 h = bfhi_of(v);
        size_t off = (size_t)e * STK_ * F_ + k;     // slot 0
        SHi[off] = h;
        SLo[off] = bfhi_of(v - bf2float(h));
    }
}

// ---------------- group barrier (32 blocks, monotone counter) ----------------
__device__ __forceinline__ void gbar(int* bar, int target) {
    __syncthreads();
    if (threadIdx.x == 0) {
        __threadfence();                 // release our global writes
        atomicAdd(bar, 1);
        while (__hip_atomic_load(bar, __ATOMIC_ACQUIRE, __HIP_MEMORY_SCOPE_AGENT) < target)
            __builtin_amdgcn_s_sleep(2);
        __threadfence();                 // acquire others' writes
    }
    __syncthreads();
}

// ---------------- 64x32 split-bf16 GEMM tile (4 waves, c[2] per wave) -------------
// wave wv: m-tiles {(wv>>1)*32, +16}, n-tile (wv&1). A rows via aOff[m] (elem offs).
__device__ __forceinline__ void gemm32(const u16* __restrict__ AHi, const u16* __restrict__ ALo,
                                       const int* aOff,
                                       const u16* __restrict__ WHi, const u16* __restrict__ WLo,
                                       int nRow0, int K, f4 c[2], int lane, int wv)
{
    const int quad = lane >> 4, mr = lane & 15;
    const int m0 = (wv >> 1) * 32 + mr, m1 = m0 + 16;
    const int n0 = nRow0 + (wv & 1) * 16 + mr;
    const int ao0 = aOff[m0], ao1 = aOff[m1];
    const u16* bh = WHi + (size_t)n0 * K;
    const u16* bl = WLo + (size_t)n0 * K;
    f4 z = {0.f, 0.f, 0.f, 0.f};
    c[0] = z; c[1] = z;
    for (int kb = 0; kb < K; kb += 32) {
        const int k = kb + quad * 8;
        sh8 a0H = *(const sh8*)(AHi + ao0 + k);
        sh8 a1H = *(const sh8*)(AHi + ao1 + k);
        sh8 a0L = *(const sh8*)(ALo + ao0 + k);
        sh8 a1L = *(const sh8*)(ALo + ao1 + k);
        sh8 bH  = *(const sh8*)(bh + k);
        sh8 bL  = *(const sh8*)(bl + k);
        c[0] = MFMA16(a0H, bH, c[0]);
        c[1] = MFMA16(a1H, bH, c[1]);
        c[0] = MFMA16(a0H, bL, c[0]);
        c[1] = MFMA16(a1H, bL, c[1]);
        c[0] = MFMA16(a0L, bH, c[0]);
        c[1] = MFMA16(a1L, bH, c[1]);
    }
}

// 64 x (<=16) tile: wave wv owns rows wv*16..+16; B rows masked to nValid.
__device__ __forceinline__ void gemm16(const u16* __restrict__ AHi, const u16* __restrict__ ALo,
                                       const int* aOff,
                                       const u16* __restrict__ WHi, const u16* __restrict__ WLo,
                                       int nValid, int K, f4& c, int lane, int wv)
{
    const int quad = lane >> 4, mr = lane & 15;
    const int m = wv * 16 + mr;
    const int ao = aOff[m];
    const bool nb = (mr < nValid);
    const u16* bh = WHi + (size_t)mr * K;
    const u16* bl = WLo + (size_t)mr * K;
    f4 z = {0.f, 0.f, 0.f, 0.f};
    c = z;
    for (int kb = 0; kb < K; kb += 32) {
        const int k = kb + quad * 8;
        sh8 aH = *(const sh8*)(AHi + ao + k);
        sh8 aL = *(const sh8*)(ALo + ao + k);
        sh8 bH = {0,0,0,0,0,0,0,0}, bL = {0,0,0,0,0,0,0,0};
        if (nb) { bH = *(const sh8*)(bh + k); bL = *(const sh8*)(bl + k); }
        c = MFMA16(aH, bH, c);
        c = MFMA16(aH, bL, c);
        c = MFMA16(aL, bH, c);
    }
}

// ---------------- epilogues (C/D map: col=lane&15, row=(lane>>4)*4+reg) ----------
__device__ __forceinline__ void ep_h32(const f4 c[2], const float* __restrict__ bias,
                                       int colBase, int e0, u16* DHi, u16* DLo,
                                       int lane, int wv)
{
    const int quad = lane >> 4, mr = lane & 15;
    const int nn = colBase + (wv & 1) * 16 + mr;
    const float bb = bias[nn];
#pragma unroll
    for (int mi = 0; mi < 2; ++mi)
#pragma unroll
    for (int r = 0; r < 4; ++r) {
        int mm = (wv >> 1) * 32 + mi * 16 + quad * 4 + r;
        float v = tanhf(c[mi][r] + bb);
        u16 hi, lo; split2(v, hi, lo);
        size_t off = (size_t)(e0 + mm) * H_ + nn;
        DHi[off] = hi; DLo[off] = lo;
    }
}

__device__ __forceinline__ void ep_stack32(const f4 c[2], const float* __restrict__ bias,
                                           int colBase, int opSel, bool useRi, int tix, int e0,
                                           const int* opsL, const int* spA,
                                           u16* SHi, u16* SLo, int lane, int wv)
{
    const int quad = lane >> 4, mr = lane & 15;
    const int nn = colBase + (wv & 1) * 16 + mr;
    const float bb = bias[nn];
#pragma unroll
    for (int mi = 0; mi < 2; ++mi)
#pragma unroll
    for (int r = 0; r < 4; ++r) {
        int mm = (wv >> 1) * 32 + mi * 16 + quad * 4 + r;
        if (opsL[mm * L_ + tix] != opSel) continue;
        int sp = spA[mm];
        int slot = useRi ? sp : sp - 1;
        slot = slot < 0 ? 0 : (slot > STK_ - 1 ? STK_ - 1 : slot);
        float v = tanhf(c[mi][r] + bb);
        u16 hi, lo; split2(v, hi, lo);
        size_t off = ((size_t)(e0 + mm) * STK_ + slot) * F_ + nn;
        SHi[off] = hi; SLo[off] = lo;
    }
}

__device__ __forceinline__ void ep_small(const f4& c, const float* __restrict__ bias,
                                         int nValid, int opSel, int tix, int e0,
                                         const int* opsL, const int* eCnt, const int* eTot,
                                         float* __restrict__ outBase, int rowStride, int ncols,
                                         int lane, int wv)
{
    const int nn = lane & 15;
    if (nn >= nValid) return;
#pragma unroll
    for (int r = 0; r < 4; ++r) {
        int mm = wv * 16 + (lane >> 4) * 4 + r;
        if (opsL[mm * L_ + tix] != opSel) continue;
        int slot = eTot[mm] - 1 - eCnt[mm];
        if (slot < 0 || slot >= 64) continue;
        float v = tanhf(c[r] + bias[nn]);
        outBase[(size_t)(e0 + mm) * rowStride + slot * ncols + nn] = v;
    }
}

// ------------- main persistent kernel: 16 groups (64 rows) x 32 blocks (32 cols) ----
// Block p: XCD-swizzled so all 32 blocks of a group share p%8 (same XCD under the
// round-robin heuristic): p = oct + 8*j + 256*gq, gid = oct + 8*gq, j in [0,32).
// 512 blocks of 256 thr @ __launch_bounds__(256,2) -> 2 blocks/CU co-resident; the
// two blocks on a CU belong to different groups, overlapping barrier/LLC stalls.
__global__ __launch_bounds__(256, 2) void grass_main(
    const int* __restrict__ ops,
    const float* __restrict__ bd, const float* __restrict__ bl, const float* __restrict__ br,
    const float* __restrict__ bsd, const float* __restrict__ bsf, const float* __restrict__ bss,
    const float* __restrict__ bbox,
    char* __restrict__ ws, float* __restrict__ out)
{
    const int tid  = threadIdx.x;
    const int lane = tid & 63, wv = tid >> 6;
    const int p    = blockIdx.x;
    const int gid  = (p & 7) + 8 * (p >> 8);   // group in [0,16)
    const int j    = (p >> 3) & 31;            // N-role in [0,32)
    const int e0   = gid * 64;

    const u16* WdHi  = (const u16*)(ws + O_WdHi);
    const u16* WdLo  = (const u16*)(ws + O_WdLo);
    const u16* WsdHi = (const u16*)(ws + O_WsdHi);
    const u16* WsdLo = (const u16*)(ws + O_WsdLo);
    const u16* WlHi  = (const u16*)(ws + O_WlHi);
    const u16* WlLo  = (const u16*)(ws + O_WlLo);
    const u16* WrHi  = (const u16*)(ws + O_WrHi);
    const u16* WrLo  = (const u16*)(ws + O_WrLo);
    const u16* WsfHi = (const u16*)(ws + O_WsfHi);
    const u16* WsfLo = (const u16*)(ws + O_WsfLo);
    const u16* WssHi = (const u16*)(ws + O_WssHi);
    const u16* WssLo = (const u16*)(ws + O_WssLo);
    const u16* WbxHi = (const u16*)(ws + O_WbxHi);
    const u16* WbxLo = (const u16*)(ws + O_WbxLo);
    u16* SHi  = (u16*)(ws + O_SHi);
    u16* SLo  = (u16*)(ws + O_SLo);
    u16* HAHi = (u16*)(ws + O_HAHi);
    u16* HALo = (u16*)(ws + O_HALo);
    u16* HSHi = (u16*)(ws + O_HSHi);
    u16* HSLo = (u16*)(ws + O_HSLo);
    int* bar = (int*)ws + gid * 32;   // 128 B spacing per group

    float* outB = out;                                   // [B][MAXB][BOX]
    float* outS = out + (size_t)B_ * MAXB_ * BOX_;       // [B][MAXSY][S]

    __shared__ int opsL[64 * L_];
    __shared__ int spA[64], beA[64], seA[64], beF[64], seF[64];
    __shared__ int aStk[64], aHH[64];
    __shared__ int sInfo[2];   // op, uniform

    for (int idx = tid; idx < 64 * L_; idx += 256) {
        int e = idx / L_, t = idx - e * L_;
        opsL[idx] = ops[(size_t)(e0 + e) * L_ + t];
    }
    __syncthreads();
    if (tid < 64) {
        spA[tid] = 1; beA[tid] = 0; seA[tid] = 0;
        int cb = 0, cs = 0;
        for (int t = 0; t < L_; ++t) {
            int o = opsL[tid * L_ + t];
            cb += (o == 0); cs += (o == 2);
        }
        beF[tid] = cb; seF[tid] = cs;
        aHH[tid]  = (e0 + tid) * H_;
        aStk[tid] = ((e0 + tid) * STK_ + 0) * F_;
    }
    __syncthreads();

    int epoch = 0;
    f4 c[2];
    f4 cs;

    for (int step = 0; step < L_; ++step) {
        const int tix = L_ - 1 - step;   // processing order = reverse of stored
        if (wv == 0) {
            int o  = opsL[lane * L_ + tix];
            int sp = spA[lane];
            unsigned long long bo = __ballot(o  == opsL[0 * L_ + tix]);
            unsigned long long bs = __ballot(sp == spA[0]);
            if (lane == 0) {
                sInfo[0] = o;
                sInfo[1] = (bo == ~0ull && bs == ~0ull) ? 1 : 0;
            }
        }
        __syncthreads();
        const int opU = sInfo[0], uni = sInfo[1];

        if (uni) {
            if (opU == 1) {
                gemm32(SHi, SLo, aStk, WdHi, WdLo, j * 32, F_, c, lane, wv);
                ep_h32(c, bd, j * 32, e0, HAHi, HALo, lane, wv);
                ++epoch; gbar(bar, 32 * epoch);
                if (j < 16) {
                    gemm32(HAHi, HALo, aHH, WlHi, WlLo, j * 32, H_, c, lane, wv);
                    ep_stack32(c, bl, j * 32, 1, false, tix, e0, opsL, spA, SHi, SLo, lane, wv);
                } else {
                    gemm32(HAHi, HALo, aHH, WrHi, WrLo, (j - 16) * 32, H_, c, lane, wv);
                    ep_stack32(c, br, (j - 16) * 32, 1, true, tix, e0, opsL, spA, SHi, SLo, lane, wv);
                }
                ++epoch; gbar(bar, 32 * epoch);
            } else if (opU == 2) {
                gemm32(SHi, SLo, aStk, WsdHi, WsdLo, j * 32, F_, c, lane, wv);
                ep_h32(c, bsd, j * 32, e0, HAHi, HALo, lane, wv);
                ++epoch; gbar(bar, 32 * epoch);
                if (j < 16) {
                    gemm32(HAHi, HALo, aHH, WsfHi, WsfLo, j * 32, H_, c, lane, wv);
                    ep_stack32(c, bsf, j * 32, 2, false, tix, e0, opsL, spA, SHi, SLo, lane, wv);
                } else if (j == 16) {
                    gemm16(HAHi, HALo, aHH, WssHi, WssLo, S_, H_, cs, lane, wv);
                    ep_small(cs, bss, S_, 2, tix, e0, opsL, seA, seF, outS, MAXSY_ * S_, S_, lane, wv);
                }
                ++epoch; gbar(bar, 32 * epoch);
            } else {
                // op0: box decode by block 0 only; no cross-block barrier needed
                if (j == 0) {
                    gemm16(SHi, SLo, aStk, WbxHi, WbxLo, BOX_, F_, cs, lane, wv);
                    ep_small(cs, bbox, BOX_, 0, tix, e0, opsL, beA, beF, outB, MAXB_ * BOX_, BOX_, lane, wv);
                }
            }
        } else {
            // general (mixed-op) path: compute everything, select per element
            gemm32(SHi, SLo, aStk, WdHi, WdLo, j * 32, F_, c, lane, wv);
            ep_h32(c, bd, j * 32, e0, HAHi, HALo, lane, wv);
            gemm32(SHi, SLo, aStk, WsdHi, WsdLo, j * 32, F_, c, lane, wv);
            ep_h32(c, bsd, j * 32, e0, HSHi, HSLo, lane, wv);
            if (j == 0) {
                gemm16(SHi, SLo, aStk, WbxHi, WbxLo, BOX_, F_, cs, lane, wv);
                ep_small(cs, bbox, BOX_, 0, tix, e0, opsL, beA, beF, outB, MAXB_ * BOX_, BOX_, lane, wv);
            }
            ++epoch; gbar(bar, 32 * epoch);
            if (j < 16) {
                gemm32(HAHi, HALo, aHH, WlHi, WlLo, j * 32, H_, c, lane, wv);
                ep_stack32(c, bl, j * 32, 1, false, tix, e0, opsL, spA, SHi, SLo, lane, wv);
                gemm32(HSHi, HSLo, aHH, WsfHi, WsfLo, j * 32, H_, c, lane, wv);
                ep_stack32(c, bsf, j * 32, 2, false, tix, e0, opsL, spA, SHi, SLo, lane, wv);
            } else {
                gemm32(HAHi, HALo, aHH, WrHi, WrLo, (j - 16) * 32, H_, c, lane, wv);
                ep_stack32(c, br, (j - 16) * 32, 1, true, tix, e0, opsL, spA, SHi, SLo, lane, wv);
                if (j == 16) {
                    gemm16(HSHi, HSLo, aHH, WssHi, WssLo, S_, H_, cs, lane, wv);
                    ep_small(cs, bss, S_, 2, tix, e0, opsL, seA, seF, outS, MAXSY_ * S_, S_, lane, wv);
                }
            }
            ++epoch; gbar(bar, 32 * epoch);
        }

        // per-element state update (block-local, all blocks identical)
        __syncthreads();
        if (tid < 64) {
            int o = opsL[tid * L_ + tix];
            if (o == 1)      spA[tid]++;
            else if (o == 2) seA[tid]++;
            else           { beA[tid]++; spA[tid]--; }
            int sp = spA[tid];
            int ti = sp - 1; ti = ti < 0 ? 0 : (ti > STK_ - 1 ? STK_ - 1 : ti);
            aStk[tid] = ((e0 + tid) * STK_ + ti) * F_;
        }
        __syncthreads();
    }
}

// ======================= fallback (round-3 fp32 kernel) =======================
__device__ __forceinline__ void fdot4(const float* __restrict__ row,
                                      const float* __restrict__ x0, const float* __restrict__ x1,
                                      const float* __restrict__ x2, const float* __restrict__ x3,
                                      int K4, float& r0, float& r1, float& r2, float& r3)
{
    const float4* r  = (const float4*)row;
    const float4* p0 = (const float4*)x0; const float4* p1 = (const float4*)x1;
    const float4* p2 = (const float4*)x2; const float4* p3 = (const float4*)x3;
    float s0=0.f,s1=0.f,s2=0.f,s3=0.f,t0=0.f,t1=0.f,t2=0.f,t3=0.f;
    for (int i = 0; i < K4; i += 2) {
        float4 w0 = r[i], w1 = r[i+1]; float4 v;
        v=p0[i]; s0+=w0.x*v.x; s0+=w0.y*v.y; s0+=w0.z*v.z; s0+=w0.w*v.w;
        v=p0[i+1]; t0+=w1.x*v.x; t0+=w1.y*v.y; t0+=w1.z*v.z; t0+=w1.w*v.w;
        v=p1[i]; s1+=w0.x*v.x; s1+=w0.y*v.y; s1+=w0.z*v.z; s1+=w0.w*v.w;
        v=p1[i+1]; t1+=w1.x*v.x; t1+=w1.y*v.y; t1+=w1.z*v.z; t1+=w1.w*v.w;
        v=p2[i]; s2+=w0.x*v.x; s2+=w0.y*v.y; s2+=w0.z*v.z; s2+=w0.w*v.w;
        v=p2[i+1]; t2+=w1.x*v.x; t2+=w1.y*v.y; t2+=w1.z*v.z; t2+=w1.w*v.w;
        v=p3[i]; s3+=w0.x*v.x; s3+=w0.y*v.y; s3+=w0.z*v.z; s3+=w0.w*v.w;
        v=p3[i+1]; t3+=w1.x*v.x; t3+=w1.y*v.y; t3+=w1.z*v.z; t3+=w1.w*v.w;
    }
    r0=s0+t0; r1=s1+t1; r2=s2+t2; r3=s3+t3;
}
__device__ __forceinline__ float fdot1(const float* __restrict__ row,
                                       const float* __restrict__ x, int K4)
{
    const float4* r = (const float4*)row; const float4* p = (const float4*)x;
    float s=0.f,t=0.f;
    for (int i = 0; i < K4; i += 2) {
        float4 w0=r[i], v0=p[i], w1=r[i+1], v1=p[i+1];
        s+=w0.x*v0.x; s+=w0.y*v0.y; s+=w0.z*v0.z; s+=w0.w*v0.w;
        t+=w1.x*v1.x; t+=w1.y*v1.y; t+=w1.z*v1.z; t+=w1.w*v1.w;
    }
    return s+t;
}
#define FB_G 4
__global__ __launch_bounds__(1024) void grass_fallback(
    const float* __restrict__ inputStacks, const int* __restrict__ ops,
    const float* __restrict__ Wd, const float* __restrict__ bd,
    const float* __restrict__ Wl, const float* __restrict__ bl,
    const float* __restrict__ Wr, const float* __restrict__ br,
    const float* __restrict__ Wsd, const float* __restrict__ bsd,
    const float* __restrict__ Wsf, const float* __restrict__ bsf,
    const float* __restrict__ Wss, const float* __restrict__ bss,
    const float* __restrict__ Wbox, const float* __restrict__ bbox,
    float* __restrict__ out)
{
    __shared__ float stk[FB_G][STK_][F_];
    __shared__ float hh[FB_G][H_];
    __shared__ float boxtmp[FB_G][MAXB_][BOX_];
    __shared__ float symtmp[FB_G][MAXSY_][S_];
    const int t = threadIdx.x, b0 = blockIdx.x * FB_G;
    for (int idx = t; idx < FB_G*F_; idx += 1024) {
        int g = idx >> 9, k = idx & (F_-1);
        stk[g][0][k] = inputStacks[(size_t)(b0+g)*F_ + k];
    }
    for (int idx = t; idx < FB_G*H_; idx += 1024) hh[idx>>10][idx&(H_-1)] = 0.f;
    int sp[FB_G], bc[FB_G], sc[FB_G];
#pragma unroll
    for (int g = 0; g < FB_G; ++g) { sp[g]=1; bc[g]=0; sc[g]=0; }
    __syncthreads();
    for (int step = 0; step < L_; ++step) {
        int op[FB_G], ti[FB_G], ri[FB_G]; bool a1=false,a2=false,a0=false;
#pragma unroll
        for (int g = 0; g < FB_G; ++g) {
            op[g] = ops[(size_t)(b0+g)*L_ + (L_-1-step)];
            int tt = sp[g]-1; tt = tt<0?0:(tt>STK_-1?STK_-1:tt); ti[g]=tt;
            int rr = sp[g]; ri[g] = rr>STK_-1?STK_-1:rr;
            a1 |= (op[g]==1); a2 |= (op[g]==2); a0 |= (op[g]==0);
        }
        const float *x0=stk[0][ti[0]], *x1=stk[1][ti[1]], *x2=stk[2][ti[2]], *x3=stk[3][ti[3]];
        if (a1) {
            float r0,r1,r2,r3; fdot4(Wd+(size_t)t*F_, x0,x1,x2,x3, F_/4, r0,r1,r2,r3);
            float bb = bd[t];
            if (op[0]==1) hh[0][t]=tanhf(r0+bb); if (op[1]==1) hh[1][t]=tanhf(r1+bb);
            if (op[2]==1) hh[2][t]=tanhf(r2+bb); if (op[3]==1) hh[3][t]=tanhf(r3+bb);
        }
        if (a2) {
            float r0,r1,r2,r3; fdot4(Wsd+(size_t)t*F_, x0,x1,x2,x3, F_/4, r0,r1,r2,r3);
            float bb = bsd[t];
            if (op[0]==2) hh[0][t]=tanhf(r0+bb); if (op[1]==2) hh[1][t]=tanhf(r1+bb);
            if (op[2]==2) hh[2][t]=tanhf(r2+bb); if (op[3]==2) hh[3][t]=tanhf(r3+bb);
        }
        if (a0 && t < FB_G*BOX_) {
            int g = t / BOX_, cc = t - g*BOX_;
            if (op[g]==0) {
                float acc = fdot1(Wbox+(size_t)cc*F_, stk[g][ti[g]], F_/4);
                boxtmp[g][bc[g]][cc] = tanhf(acc + bbox[cc]);
            }
        }
        __syncthreads();
        if (a1) {
            if (t < F_) {
                float r0,r1,r2,r3; fdot4(Wl+(size_t)t*H_, hh[0],hh[1],hh[2],hh[3], H_/4, r0,r1,r2,r3);
                float bb = bl[t];
                if (op[0]==1) stk[0][ti[0]][t]=tanhf(r0+bb); if (op[1]==1) stk[1][ti[1]][t]=tanhf(r1+bb);
                if (op[2]==1) stk[2][ti[2]][t]=tanhf(r2+bb); if (op[3]==1) stk[3][ti[3]][t]=tanhf(r3+bb);
            } else {
                int m = t - F_;
                float r0,r1,r2,r3; fdot4(Wr+(size_t)m*H_, hh[0],hh[1],hh[2],hh[3], H_/4, r0,r1,r2,r3);
                float bb = br[m];
                if (op[0]==1) stk[0][ri[0]][m]=tanhf(r0+bb); if (op[1]==1) stk[1][ri[1]][m]=tanhf(r1+bb);
                if (op[2]==1) stk[2][ri[2]][m]=tanhf(r2+bb); if (op[3]==1) stk[3][ri[3]][m]=tanhf(r3+bb);
            }
        }
        if (a2) {
            if (t < F_) {
                float r0,r1,r2,r3; fdot4(Wsf+(size_t)t*H_, hh[0],hh[1],hh[2],hh[3], H_/4, r0,r1,r2,r3);
                float bb = bsf[t];
                if (op[0]==2) stk[0][ti[0]][t]=tanhf(r0+bb); if (op[1]==2) stk[1][ti[1]][t]=tanhf(r1+bb);
                if (op[2]==2) stk[2][ti[2]][t]=tanhf(r2+bb); if (op[3]==2) stk[3][ti[3]][t]=tanhf(r3+bb);
            } else if (t < F_ + FB_G*S_) {
                int idx = t - F_, g = idx >> 3, cc = idx & 7;
                if (op[g]==2) {
                    float acc = fdot1(Wss+(size_t)cc*H_, hh[g], H_/4);
                    symtmp[g][sc[g]][cc] = tanhf(acc + bss[cc]);
                }
            }
        }
        __syncthreads();
#pragma unroll
        for (int g = 0; g < FB_G; ++g) {
            if (op[g]==1) sp[g]++;
            else if (op[g]==2) sc[g]++;
            else { bc[g]++; sp[g]--; }
        }
    }
#pragma unroll
    for (int g = 0; g < FB_G; ++g) {
        int b = b0 + g;
        float* ob = out + (size_t)b * MAXB_ * BOX_;
        for (int idx = t; idx < MAXB_*BOX_; idx += 1024) {
            int jj = idx / BOX_, cc = idx - jj*BOX_;
            int e = bc[g] - 1 - jj;
            ob[idx] = (e >= 0) ? boxtmp[g][e][cc] : 0.f;
        }
        float* os = out + (size_t)B_*MAXB_*BOX_ + (size_t)b * MAXSY_ * S_;
        for (int idx = t; idx < MAXSY_*S_; idx += 1024) {
            int jj = idx >> 3, cc = idx & 7;
            int e = sc[g] - 1 - jj;
            os[idx] = (e >= 0) ? symtmp[g][e][cc] : 0.f;
        }
    }
}

// ---------------- launcher ----------------
extern "C" void kernel_launch(void* const* d_in, const int* in_sizes, int n_in,
                              void* d_out, int out_size, void* d_ws, size_t ws_size,
                              hipStream_t stream) {
    (void)in_sizes; (void)n_in;
    const float* X    = (const float*)d_in[0];
    const int*   ops  = (const int*)d_in[1];
    const float* Wd   = (const float*)d_in[2];  const float* bd   = (const float*)d_in[3];
    const float* Wl   = (const float*)d_in[4];  const float* bl   = (const float*)d_in[5];
    const float* Wr   = (const float*)d_in[6];  const float* br   = (const float*)d_in[7];
    const float* Wsd  = (const float*)d_in[8];  const float* bsd  = (const float*)d_in[9];
    const float* Wsf  = (const float*)d_in[10]; const float* bsf  = (const float*)d_in[11];
    const float* Wss  = (const float*)d_in[12]; const float* bss  = (const float*)d_in[13];
    const float* Wbox = (const float*)d_in[14]; const float* bbox = (const float*)d_in[15];
    float* out = (float*)d_out;

    if (ws_size < WS_NEED) {
        grass_fallback<<<dim3(B_/FB_G), dim3(1024), 0, stream>>>(
            X, ops, Wd, bd, Wl, bl, Wr, br, Wsd, bsd, Wsf, bsf, Wss, bss, Wbox, bbox, out);
        return;
    }
    char* ws = (char*)d_ws;
    hipMemsetAsync(d_out, 0, (size_t)out_size * sizeof(float), stream);  // zero-pad slots
    hipMemsetAsync(ws, 0, 4096, stream);                                 // barrier counters
    grass_prep<<<dim3(512), dim3(256), 0, stream>>>(X, Wd, Wl, Wr, Wsd, Wsf, Wss, Wbox, ws);
    grass_main<<<dim3(512), dim3(256), 0, stream>>>(ops, bd, bl, br, bsd, bsf, bss, bbox, ws, out);
}

// Round 6
// 5153.455 us; speedup vs baseline: 3.3406x; 3.3406x over previous
//
#include <hip/hip_runtime.h>
#include <stdint.h>

// ---------------- problem constants ----------------
#define B_     1024
#define F_     512
#define H_     1024
#define S_     8
#define BOX_   12
#define MAXB_  64
#define MAXSY_ 64
#define L_     126
#define STK_   3

typedef unsigned short u16;
typedef unsigned int   u32;
typedef __attribute__((ext_vector_type(8))) short sh8;   // 8 bf16 (4 VGPRs)
typedef __attribute__((ext_vector_type(4))) int   i4;    // asm payload (16 B)
typedef __attribute__((ext_vector_type(4))) float f4;    // MFMA accumulator

#define MFMA16(a,b,c) __builtin_amdgcn_mfma_f32_16x16x32_bf16((a),(b),(c),0,0,0)

// ---------------- ws layout (bytes) ----------------
constexpr size_t PL_HF = (size_t)H_ * F_ * 2;      // 1 MB  (Wd, Wsd planes)
constexpr size_t PL_FH = (size_t)F_ * H_ * 2;      // 1 MB  (Wl, Wr, Wsf planes)
constexpr size_t PL_SS = 16384;                    // S*H*2
constexpr size_t PL_BX = 16384;                    // BOX*F*2=12288, padded
constexpr size_t O_WdHi  = 4096;
constexpr size_t O_WdLo  = O_WdHi  + PL_HF;
constexpr size_t O_WsdHi = O_WdLo  + PL_HF;
constexpr size_t O_WsdLo = O_WsdHi + PL_HF;
constexpr size_t O_WlHi  = O_WsdLo + PL_HF;
constexpr size_t O_WlLo  = O_WlHi  + PL_FH;
constexpr size_t O_WrHi  = O_WlLo  + PL_FH;
constexpr size_t O_WrLo  = O_WrHi  + PL_FH;
constexpr size_t O_WsfHi = O_WrLo  + PL_FH;
constexpr size_t O_WsfLo = O_WsfHi + PL_FH;
constexpr size_t O_WssHi = O_WsfLo + PL_FH;
constexpr size_t O_WssLo = O_WssHi + PL_SS;
constexpr size_t O_WbxHi = O_WssLo + PL_SS;
constexpr size_t O_WbxLo = O_WbxHi + PL_BX;
constexpr size_t SZ_STK  = (size_t)B_ * STK_ * F_ * 2;   // 3 MB per plane
constexpr size_t O_SHi   = O_WbxLo + PL_BX;
constexpr size_t O_SLo   = O_SHi   + SZ_STK;
constexpr size_t SZ_H    = (size_t)B_ * H_ * 2;          // 2 MB per plane
constexpr size_t O_HAHi  = O_SLo   + SZ_STK;
constexpr size_t O_HALo  = O_HAHi  + SZ_H;
constexpr size_t O_HSHi  = O_HALo  + SZ_H;
constexpr size_t O_HSLo  = O_HSHi  + SZ_H;
constexpr size_t WS_NEED = O_HSLo  + SZ_H;               // ~24.1 MB

// ---------------- numeric helpers ----------------
__device__ __forceinline__ float bf2float(u16 h) {
    union { u32 u; float f; } v; v.u = ((u32)h) << 16; return v.f;
}
__device__ __forceinline__ u16 bfhi_of(float f) {           // RNE fp32->bf16
    union { float f; u32 u; } v; v.f = f;
    u32 u = v.u;
    return (u16)((u + 0x7fffu + ((u >> 16) & 1u)) >> 16);
}
__device__ __forceinline__ void split2(float x, u16& hi, u16& lo) {
    hi = bfhi_of(x);
    lo = bfhi_of(x - bf2float(hi));
}

// ---------------- device-coherent (sc0 sc1) memory ops, fence-free ----------------
// Loads/stores that bypass L1/L2 and hit the device coherence point (LLC).
// Batched loads share one s_waitcnt -> MLP=8 against LLC latency.
__device__ __forceinline__ void cload8(i4& d0, i4& d1, i4& d2, i4& d3,
                                       i4& d4, i4& d5, i4& d6, i4& d7,
    const u16* p0, const u16* p1, const u16* p2, const u16* p3,
    const u16* p4, const u16* p5, const u16* p6, const u16* p7)
{
    asm volatile(
        "global_load_dwordx4 %0, %8, off sc0 sc1\n\t"
        "global_load_dwordx4 %1, %9, off sc0 sc1\n\t"
        "global_load_dwordx4 %2, %10, off sc0 sc1\n\t"
        "global_load_dwordx4 %3, %11, off sc0 sc1\n\t"
        "global_load_dwordx4 %4, %12, off sc0 sc1\n\t"
        "global_load_dwordx4 %5, %13, off sc0 sc1\n\t"
        "global_load_dwordx4 %6, %14, off sc0 sc1\n\t"
        "global_load_dwordx4 %7, %15, off sc0 sc1\n\t"
        "s_waitcnt vmcnt(0)"
        : "=&v"(d0),"=&v"(d1),"=&v"(d2),"=&v"(d3),
          "=&v"(d4),"=&v"(d5),"=&v"(d6),"=&v"(d7)
        : "v"(p0),"v"(p1),"v"(p2),"v"(p3),"v"(p4),"v"(p5),"v"(p6),"v"(p7));
}
__device__ __forceinline__ void cload4(i4& d0, i4& d1, i4& d2, i4& d3,
    const u16* p0, const u16* p1, const u16* p2, const u16* p3)
{
    asm volatile(
        "global_load_dwordx4 %0, %4, off sc0 sc1\n\t"
        "global_load_dwordx4 %1, %5, off sc0 sc1\n\t"
        "global_load_dwordx4 %2, %6, off sc0 sc1\n\t"
        "global_load_dwordx4 %3, %7, off sc0 sc1\n\t"
        "s_waitcnt vmcnt(0)"
        : "=&v"(d0),"=&v"(d1),"=&v"(d2),"=&v"(d3)
        : "v"(p0),"v"(p1),"v"(p2),"v"(p3));
}
__device__ __forceinline__ void cstore2(u16* p, u16 v) {
    asm volatile("global_store_short %0, %1, off sc0 sc1"
                 :: "v"(p), "v"((u32)v) : "memory");
}
__device__ __forceinline__ void vdrain() {
    asm volatile("s_waitcnt vmcnt(0)" ::: "memory");
}
__device__ __forceinline__ sh8 as_sh8(i4 v) { return __builtin_bit_cast(sh8, v); }

// ---------------- prep: split weights + input stacks to bf16 hi/lo ----------------
__device__ void split_range(const float* __restrict__ s, u16* hi, u16* lo,
                            int n, int t0, int stride) {
    for (int i = t0; i < n; i += stride) {
        float v = s[i];
        u16 h = bfhi_of(v);
        hi[i] = h;
        lo[i] = bfhi_of(v - bf2float(h));
    }
}

__global__ void grass_prep(const float* __restrict__ X,
                           const float* __restrict__ Wd, const float* __restrict__ Wl,
                           const float* __restrict__ Wr, const float* __restrict__ Wsd,
                           const float* __restrict__ Wsf, const float* __restrict__ Wss,
                           const float* __restrict__ Wbox, char* __restrict__ ws)
{
    const int t0 = blockIdx.x * blockDim.x + threadIdx.x;
    const int st = gridDim.x * blockDim.x;
    split_range(Wd,  (u16*)(ws + O_WdHi),  (u16*)(ws + O_WdLo),  H_ * F_, t0, st);
    split_range(Wsd, (u16*)(ws + O_WsdHi), (u16*)(ws + O_WsdLo), H_ * F_, t0, st);
    split_range(Wl,  (u16*)(ws + O_WlHi),  (u16*)(ws + O_WlLo),  F_ * H_, t0, st);
    split_range(Wr,  (u16*)(ws + O_WrHi),  (u16*)(ws + O_WrLo),  F_ * H_, t0, st);
    split_range(Wsf, (u16*)(ws + O_WsfHi), (u16*)(ws + O_WsfLo), F_ * H_, t0, st);
    split_range(Wss, (u16*)(ws + O_WssHi), (u16*)(ws + O_WssLo), S_ * H_, t0, st);
    split_range(Wbox,(u16*)(ws + O_WbxHi), (u16*)(ws + O_WbxLo), BOX_ * F_, t0, st);
    u16* SHi = (u16*)(ws + O_SHi);
    u16* SLo = (u16*)(ws + O_SLo);
    for (int i = t0; i < B_ * F_; i += st) {
        int e = i >> 9, k = i & (F_ - 1);
        float v = X[i];
        u16 h = bfhi_of(v);
        size_t off = (size_t)e * STK_ * F_ + k;     // slot 0
        SHi[off] = h;
        SLo[off] = bfhi_of(v - bf2float(h));
    }
}

// -------- group barrier: fence-FREE (no L2 writeback/invalidate). Ordering is by
// completion at the coherence point: all exchange traffic uses sc0sc1 accesses,
// each wave drains vmcnt before s_barrier, then one relaxed agent atomic. --------
__device__ __forceinline__ void gbar(int* bar, int target) {
    vdrain();                     // this wave's coherent stores are at LLC
    __syncthreads();              // => whole block's stores are at LLC
    if (threadIdx.x == 0) {
        __hip_atomic_fetch_add(bar, 1, __ATOMIC_RELAXED, __HIP_MEMORY_SCOPE_AGENT);
        while (__hip_atomic_load(bar, __ATOMIC_RELAXED, __HIP_MEMORY_SCOPE_AGENT) < target)
            __builtin_amdgcn_s_sleep(2);
    }
    __syncthreads();
}

// ---------------- 64x64 split-bf16 GEMM tile (4 waves, 2x2 regblock/wave) ----------
// A (activations) via coherent batched loads; W (weights) via normal cached loads.
__device__ __forceinline__ void gemm64(const u16* __restrict__ AHi, const u16* __restrict__ ALo,
                                       const int* aOff,
                                       const u16* __restrict__ WHi, const u16* __restrict__ WLo,
                                       int nRow0, int K, f4 c[2][2], int lane, int wv)
{
    const int quad = lane >> 4, mr = lane & 15;
    const int mh = wv & 1, nh = (wv >> 1) & 1;
    const int m0 = (mh * 2) * 16 + mr, m1 = m0 + 16;
    const int n0 = nRow0 + (nh * 2) * 16 + mr, n1 = n0 + 16;
    const int ao0 = aOff[m0], ao1 = aOff[m1];
    const u16* b0h = WHi + (size_t)n0 * K;
    const u16* b1h = WHi + (size_t)n1 * K;
    const u16* b0l = WLo + (size_t)n0 * K;
    const u16* b1l = WLo + (size_t)n1 * K;
    f4 z = {0.f, 0.f, 0.f, 0.f};
    c[0][0] = z; c[0][1] = z; c[1][0] = z; c[1][1] = z;
    for (int kb = 0; kb < K; kb += 64) {
        const int k0 = kb + quad * 8, k1 = k0 + 32;
        // cached weight loads (L2-hot; never invalidated now)
        sh8 B0H0 = *(const sh8*)(b0h + k0), B1H0 = *(const sh8*)(b1h + k0);
        sh8 B0L0 = *(const sh8*)(b0l + k0), B1L0 = *(const sh8*)(b1l + k0);
        sh8 B0H1 = *(const sh8*)(b0h + k1), B1H1 = *(const sh8*)(b1h + k1);
        sh8 B0L1 = *(const sh8*)(b0l + k1), B1L1 = *(const sh8*)(b1l + k1);
        // coherent activation loads, batched (MLP=8)
        i4 a0,a1,a2,a3,a4,a5,a6,a7;
        cload8(a0,a1,a2,a3,a4,a5,a6,a7,
               AHi+ao0+k0, AHi+ao1+k0, ALo+ao0+k0, ALo+ao1+k0,
               AHi+ao0+k1, AHi+ao1+k1, ALo+ao0+k1, ALo+ao1+k1);
        sh8 A0H0=as_sh8(a0), A1H0=as_sh8(a1), A0L0=as_sh8(a2), A1L0=as_sh8(a3);
        sh8 A0H1=as_sh8(a4), A1H1=as_sh8(a5), A0L1=as_sh8(a6), A1L1=as_sh8(a7);
        c[0][0]=MFMA16(A0H0,B0H0,c[0][0]); c[0][1]=MFMA16(A0H0,B1H0,c[0][1]);
        c[1][0]=MFMA16(A1H0,B0H0,c[1][0]); c[1][1]=MFMA16(A1H0,B1H0,c[1][1]);
        c[0][0]=MFMA16(A0H0,B0L0,c[0][0]); c[0][1]=MFMA16(A0H0,B1L0,c[0][1]);
        c[1][0]=MFMA16(A1H0,B0L0,c[1][0]); c[1][1]=MFMA16(A1H0,B1L0,c[1][1]);
        c[0][0]=MFMA16(A0L0,B0H0,c[0][0]); c[0][1]=MFMA16(A0L0,B1H0,c[0][1]);
        c[1][0]=MFMA16(A1L0,B0H0,c[1][0]); c[1][1]=MFMA16(A1L0,B1H0,c[1][1]);
        c[0][0]=MFMA16(A0H1,B0H1,c[0][0]); c[0][1]=MFMA16(A0H1,B1H1,c[0][1]);
        c[1][0]=MFMA16(A1H1,B0H1,c[1][0]); c[1][1]=MFMA16(A1H1,B1H1,c[1][1]);
        c[0][0]=MFMA16(A0H1,B0L1,c[0][0]); c[0][1]=MFMA16(A0H1,B1L1,c[0][1]);
        c[1][0]=MFMA16(A1H1,B0L1,c[1][0]); c[1][1]=MFMA16(A1H1,B1L1,c[1][1]);
        c[0][0]=MFMA16(A0L1,B0H1,c[0][0]); c[0][1]=MFMA16(A0L1,B1H1,c[0][1]);
        c[1][0]=MFMA16(A1L1,B0H1,c[1][0]); c[1][1]=MFMA16(A1L1,B1H1,c[1][1]);
    }
}

// 64 x (<=16) tile: wave wv owns rows wv*16..+16; B rows masked to nValid.
__device__ __forceinline__ void gemm16(const u16* __restrict__ AHi, const u16* __restrict__ ALo,
                                       const int* aOff,
                                       const u16* __restrict__ WHi, const u16* __restrict__ WLo,
                                       int nValid, int K, f4& c, int lane, int wv)
{
    const int quad = lane >> 4, mr = lane & 15;
    const int m = wv * 16 + mr;
    const int ao = aOff[m];
    const bool nb = (mr < nValid);
    const u16* bh = WHi + (size_t)mr * K;
    const u16* bl = WLo + (size_t)mr * K;
    f4 z = {0.f, 0.f, 0.f, 0.f};
    c = z;
    for (int kb = 0; kb < K; kb += 64) {
        const int k0 = kb + quad * 8, k1 = k0 + 32;
        sh8 bH0 = {0,0,0,0,0,0,0,0}, bL0 = {0,0,0,0,0,0,0,0};
        sh8 bH1 = {0,0,0,0,0,0,0,0}, bL1 = {0,0,0,0,0,0,0,0};
        if (nb) {
            bH0 = *(const sh8*)(bh + k0); bL0 = *(const sh8*)(bl + k0);
            bH1 = *(const sh8*)(bh + k1); bL1 = *(const sh8*)(bl + k1);
        }
        i4 a0,a1,a2,a3;
        cload4(a0,a1,a2,a3, AHi+ao+k0, ALo+ao+k0, AHi+ao+k1, ALo+ao+k1);
        sh8 aH0=as_sh8(a0), aL0=as_sh8(a1), aH1=as_sh8(a2), aL1=as_sh8(a3);
        c = MFMA16(aH0, bH0, c);
        c = MFMA16(aH0, bL0, c);
        c = MFMA16(aL0, bH0, c);
        c = MFMA16(aH1, bH1, c);
        c = MFMA16(aH1, bL1, c);
        c = MFMA16(aL1, bH1, c);
    }
}

// ---------------- epilogues (C/D map: col=lane&15, row=(lane>>4)*4+reg) ----------
__device__ __forceinline__ void ep_h(const f4 c[2][2], const float* __restrict__ bias,
                                     int colBase, int e0, u16* DHi, u16* DLo,
                                     int lane, int wv)
{
    const int quad = lane >> 4, mr = lane & 15;
    const int mh = wv & 1, nh = (wv >> 1) & 1;
#pragma unroll
    for (int mi = 0; mi < 2; ++mi)
#pragma unroll
    for (int ni = 0; ni < 2; ++ni)
#pragma unroll
    for (int r = 0; r < 4; ++r) {
        int mm = (mh * 2 + mi) * 16 + quad * 4 + r;
        int nn = (nh * 2 + ni) * 16 + mr;
        float v = tanhf(c[mi][ni][r] + bias[colBase + nn]);
        u16 hi, lo; split2(v, hi, lo);
        size_t off = (size_t)(e0 + mm) * H_ + colBase + nn;
        cstore2(DHi + off, hi);
        cstore2(DLo + off, lo);
    }
}

__device__ __forceinline__ void ep_stack(const f4 c[2][2], const float* __restrict__ bias,
                                         int colBase, int opSel, bool useRi, int tix, int e0,
                                         const int* opsL, const int* spA,
                                         u16* SHi, u16* SLo, int lane, int wv)
{
    const int quad = lane >> 4, mr = lane & 15;
    const int mh = wv & 1, nh = (wv >> 1) & 1;
#pragma unroll
    for (int mi = 0; mi < 2; ++mi)
#pragma unroll
    for (int ni = 0; ni < 2; ++ni)
#pragma unroll
    for (int r = 0; r < 4; ++r) {
        int mm = (mh * 2 + mi) * 16 + quad * 4 + r;
        int nn = (nh * 2 + ni) * 16 + mr;
        if (opsL[mm * L_ + tix] != opSel) continue;
        int sp = spA[mm];
        int slot = useRi ? sp : sp - 1;
        slot = slot < 0 ? 0 : (slot > STK_ - 1 ? STK_ - 1 : slot);
        float v = tanhf(c[mi][ni][r] + bias[colBase + nn]);
        u16 hi, lo; split2(v, hi, lo);
        size_t off = ((size_t)(e0 + mm) * STK_ + slot) * F_ + colBase + nn;
        cstore2(SHi + off, hi);
        cstore2(SLo + off, lo);
    }
}

__device__ __forceinline__ void ep_small(const f4& c, const float* __restrict__ bias,
                                         int nValid, int opSel, int tix, int e0,
                                         const int* opsL, const int* eCnt, const int* eTot,
                                         float* __restrict__ outBase, int rowStride, int ncols,
                                         int lane, int wv)
{
    const int nn = lane & 15;
    if (nn >= nValid) return;
#pragma unroll
    for (int r = 0; r < 4; ++r) {
        int mm = wv * 16 + (lane >> 4) * 4 + r;
        if (opsL[mm * L_ + tix] != opSel) continue;
        int slot = eTot[mm] - 1 - eCnt[mm];
        if (slot < 0 || slot >= 64) continue;
        float v = tanhf(c[r] + bias[nn]);
        outBase[(size_t)(e0 + mm) * rowStride + slot * ncols + nn] = v;  // host-only reader
    }
}

// ---------------- main persistent kernel: 16 groups (64 rows) x 16 blocks ----------
__global__ __launch_bounds__(256, 2) void grass_main(
    const int* __restrict__ ops,
    const float* __restrict__ bd, const float* __restrict__ bl, const float* __restrict__ br,
    const float* __restrict__ bsd, const float* __restrict__ bsf, const float* __restrict__ bss,
    const float* __restrict__ bbox,
    char* __restrict__ ws, float* __restrict__ out)
{
    const int tid  = threadIdx.x;
    const int lane = tid & 63, wv = tid >> 6;
    const int gid  = blockIdx.x >> 4;     // group (owns 64 batch rows)
    const int j    = blockIdx.x & 15;     // N-tile role within group
    const int e0   = gid * 64;

    const u16* WdHi  = (const u16*)(ws + O_WdHi);
    const u16* WdLo  = (const u16*)(ws + O_WdLo);
    const u16* WsdHi = (const u16*)(ws + O_WsdHi);
    const u16* WsdLo = (const u16*)(ws + O_WsdLo);
    const u16* WlHi  = (const u16*)(ws + O_WlHi);
    const u16* WlLo  = (const u16*)(ws + O_WlLo);
    const u16* WrHi  = (const u16*)(ws + O_WrHi);
    const u16* WrLo  = (const u16*)(ws + O_WrLo);
    const u16* WsfHi = (const u16*)(ws + O_WsfHi);
    const u16* WsfLo = (const u16*)(ws + O_WsfLo);
    const u16* WssHi = (const u16*)(ws + O_WssHi);
    const u16* WssLo = (const u16*)(ws + O_WssLo);
    const u16* WbxHi = (const u16*)(ws + O_WbxHi);
    const u16* WbxLo = (const u16*)(ws + O_WbxLo);
    u16* SHi  = (u16*)(ws + O_SHi);
    u16* SLo  = (u16*)(ws + O_SLo);
    u16* HAHi = (u16*)(ws + O_HAHi);
    u16* HALo = (u16*)(ws + O_HALo);
    u16* HSHi = (u16*)(ws + O_HSHi);
    u16* HSLo = (u16*)(ws + O_HSLo);
    int* bar = (int*)ws + gid * 32;   // 128 B spacing per group

    float* outB = out;                                   // [B][MAXB][BOX]
    float* outS = out + (size_t)B_ * MAXB_ * BOX_;       // [B][MAXSY][S]

    __shared__ int opsL[64 * L_];
    __shared__ int spA[64], beA[64], seA[64], beF[64], seF[64];
    __shared__ int aStk[64], aHH[64];
    __shared__ int sInfo[2];   // op, uniform

    for (int idx = tid; idx < 64 * L_; idx += 256) {
        int e = idx / L_, t = idx - e * L_;
        opsL[idx] = ops[(size_t)(e0 + e) * L_ + t];
    }
    __syncthreads();
    if (tid < 64) {
        spA[tid] = 1; beA[tid] = 0; seA[tid] = 0;
        int cb = 0, cs = 0;
        for (int t = 0; t < L_; ++t) {
            int o = opsL[tid * L_ + t];
            cb += (o == 0); cs += (o == 2);
        }
        beF[tid] = cb; seF[tid] = cs;
        aHH[tid]  = (e0 + tid) * H_;
        aStk[tid] = ((e0 + tid) * STK_ + 0) * F_;
    }
    __syncthreads();

    int epoch = 0;
    f4 c[2][2];
    f4 cs;

    for (int step = 0; step < L_; ++step) {
        const int tix = L_ - 1 - step;   // processing order = reverse of stored
        if (wv == 0) {
            int o  = opsL[lane * L_ + tix];
            int sp = spA[lane];
            unsigned long long bo = __ballot(o  == opsL[0 * L_ + tix]);
            unsigned long long bs = __ballot(sp == spA[0]);
            if (lane == 0) {
                sInfo[0] = o;
                sInfo[1] = (bo == ~0ull && bs == ~0ull) ? 1 : 0;
            }
        }
        __syncthreads();
        const int opU = sInfo[0], uni = sInfo[1];

        if (uni) {
            if (opU == 1) {
                gemm64(SHi, SLo, aStk, WdHi, WdLo, j * 64, F_, c, lane, wv);
                ep_h(c, bd, j * 64, e0, HAHi, HALo, lane, wv);
                ++epoch; gbar(bar, 16 * epoch);
                if (j < 8) {
                    gemm64(HAHi, HALo, aHH, WlHi, WlLo, j * 64, H_, c, lane, wv);
                    ep_stack(c, bl, (j & 7) * 64, 1, false, tix, e0, opsL, spA, SHi, SLo, lane, wv);
                } else {
                    gemm64(HAHi, HALo, aHH, WrHi, WrLo, (j - 8) * 64, H_, c, lane, wv);
                    ep_stack(c, br, (j & 7) * 64, 1, true, tix, e0, opsL, spA, SHi, SLo, lane, wv);
                }
                ++epoch; gbar(bar, 16 * epoch);
            } else if (opU == 2) {
                gemm64(SHi, SLo, aStk, WsdHi, WsdLo, j * 64, F_, c, lane, wv);
                ep_h(c, bsd, j * 64, e0, HAHi, HALo, lane, wv);
                ++epoch; gbar(bar, 16 * epoch);
                if (j < 8) {
                    gemm64(HAHi, HALo, aHH, WsfHi, WsfLo, j * 64, H_, c, lane, wv);
                    ep_stack(c, bsf, (j & 7) * 64, 2, false, tix, e0, opsL, spA, SHi, SLo, lane, wv);
                } else if (j == 8) {
                    gemm16(HAHi, HALo, aHH, WssHi, WssLo, S_, H_, cs, lane, wv);
                    ep_small(cs, bss, S_, 2, tix, e0, opsL, seA, seF, outS, MAXSY_ * S_, S_, lane, wv);
                }
                ++epoch; gbar(bar, 16 * epoch);
            } else {
                // op0: box decode by block 0 only; no cross-block barrier needed
                if (j == 0) {
                    gemm16(SHi, SLo, aStk, WbxHi, WbxLo, BOX_, F_, cs, lane, wv);
                    ep_small(cs, bbox, BOX_, 0, tix, e0, opsL, beA, beF, outB, MAXB_ * BOX_, BOX_, lane, wv);
                }
            }
        } else {
            // general (mixed-op) path: compute everything, select per element
            gemm64(SHi, SLo, aStk, WdHi, WdLo, j * 64, F_, c, lane, wv);
            ep_h(c, bd, j * 64, e0, HAHi, HALo, lane, wv);
            gemm64(SHi, SLo, aStk, WsdHi, WsdLo, j * 64, F_, c, lane, wv);
            ep_h(c, bsd, j * 64, e0, HSHi, HSLo, lane, wv);
            if (j == 0) {
                gemm16(SHi, SLo, aStk, WbxHi, WbxLo, BOX_, F_, cs, lane, wv);
                ep_small(cs, bbox, BOX_, 0, tix, e0, opsL, beA, beF, outB, MAXB_ * BOX_, BOX_, lane, wv);
            }
            ++epoch; gbar(bar, 16 * epoch);
            if (j < 8) {
                gemm64(HAHi, HALo, aHH, WlHi, WlLo, j * 64, H_, c, lane, wv);
                ep_stack(c, bl, (j & 7) * 64, 1, false, tix, e0, opsL, spA, SHi, SLo, lane, wv);
                gemm64(HSHi, HSLo, aHH, WsfHi, WsfLo, j * 64, H_, c, lane, wv);
                ep_stack(c, bsf, (j & 7) * 64, 2, false, tix, e0, opsL, spA, SHi, SLo, lane, wv);
            } else {
                gemm64(HAHi, HALo, aHH, WrHi, WrLo, (j - 8) * 64, H_, c, lane, wv);
                ep_stack(c, br, (j & 7) * 64, 1, true, tix, e0, opsL, spA, SHi, SLo, lane, wv);
                if (j == 8) {
                    gemm16(HSHi, HSLo, aHH, WssHi, WssLo, S_, H_, cs, lane, wv);
                    ep_small(cs, bss, S_, 2, tix, e0, opsL, seA, seF, outS, MAXSY_ * S_, S_, lane, wv);
                }
            }
            ++epoch; gbar(bar, 16 * epoch);
        }

        // per-element state update (block-local, all blocks identical)
        __syncthreads();
        if (tid < 64) {
            int o = opsL[tid * L_ + tix];
            if (o == 1)      spA[tid]++;
            else if (o == 2) seA[tid]++;
            else           { beA[tid]++; spA[tid]--; }
            int sp = spA[tid];
            int ti = sp - 1; ti = ti < 0 ? 0 : (ti > STK_ - 1 ? STK_ - 1 : ti);
            aStk[tid] = ((e0 + tid) * STK_ + ti) * F_;
        }
        __syncthreads();
    }
}

// ======================= fallback (round-3 fp32 kernel) =======================
__device__ __forceinline__ void fdot4(const float* __restrict__ row,
                                      const float* __restrict__ x0, const float* __restrict__ x1,
                                      const float* __restrict__ x2, const float* __restrict__ x3,
                                      int K4, float& r0, float& r1, float& r2, float& r3)
{
    const float4* r  = (const float4*)row;
    const float4* p0 = (const float4*)x0; const float4* p1 = (const float4*)x1;
    const float4* p2 = (const float4*)x2; const float4* p3 = (const float4*)x3;
    float s0=0.f,s1=0.f,s2=0.f,s3=0.f,t0=0.f,t1=0.f,t2=0.f,t3=0.f;
    for (int i = 0; i < K4; i += 2) {
        float4 w0 = r[i], w1 = r[i+1]; float4 v;
        v=p0[i]; s0+=w0.x*v.x; s0+=w0.y*v.y; s0+=w0.z*v.z; s0+=w0.w*v.w;
        v=p0[i+1]; t0+=w1.x*v.x; t0+=w1.y*v.y; t0+=w1.z*v.z; t0+=w1.w*v.w;
        v=p1[i]; s1+=w0.x*v.x; s1+=w0.y*v.y; s1+=w0.z*v.z; s1+=w0.w*v.w;
        v=p1[i+1]; t1+=w1.x*v.x; t1+=w1.y*v.y; t1+=w1.z*v.z; t1+=w1.w*v.w;
        v=p2[i]; s2+=w0.x*v.x; s2+=w0.y*v.y; s2+=w0.z*v.z; s2+=w0.w*v.w;
        v=p2[i+1]; t2+=w1.x*v.x; t2+=w1.y*v.y; t2+=w1.z*v.z; t2+=w1.w*v.w;
        v=p3[i]; s3+=w0.x*v.x; s3+=w0.y*v.y; s3+=w0.z*v.z; s3+=w0.w*v.w;
        v=p3[i+1]; t3+=w1.x*v.x; t3+=w1.y*v.y; t3+=w1.z*v.z; t3+=w1.w*v.w;
    }
    r0=s0+t0; r1=s1+t1; r2=s2+t2; r3=s3+t3;
}
__device__ __forceinline__ float fdot1(const float* __restrict__ row,
                                       const float* __restrict__ x, int K4)
{
    const float4* r = (const float4*)row; const float4* p = (const float4*)x;
    float s=0.f,t=0.f;
    for (int i = 0; i < K4; i += 2) {
        float4 w0=r[i], v0=p[i], w1=r[i+1], v1=p[i+1];
        s+=w0.x*v0.x; s+=w0.y*v0.y; s+=w0.z*v0.z; s+=w0.w*v0.w;
        t+=w1.x*v1.x; t+=w1.y*v1.y; t+=w1.z*v1.z; t+=w1.w*v1.w;
    }
    return s+t;
}
#define FB_G 4
__global__ __launch_bounds__(1024) void grass_fallback(
    const float* __restrict__ inputStacks, const int* __restrict__ ops,
    const float* __restrict__ Wd, const float* __restrict__ bd,
    const float* __restrict__ Wl, const float* __restrict__ bl,
    const float* __restrict__ Wr, const float* __restrict__ br,
    const float* __restrict__ Wsd, const float* __restrict__ bsd,
    const float* __restrict__ Wsf, const float* __restrict__ bsf,
    const float* __restrict__ Wss, const float* __restrict__ bss,
    const float* __restrict__ Wbox, const float* __restrict__ bbox,
    float* __restrict__ out)
{
    __shared__ float stk[FB_G][STK_][F_];
    __shared__ float hh[FB_G][H_];
    __shared__ float boxtmp[FB_G][MAXB_][BOX_];
    __shared__ float symtmp[FB_G][MAXSY_][S_];
    const int t = threadIdx.x, b0 = blockIdx.x * FB_G;
    for (int idx = t; idx < FB_G*F_; idx += 1024) {
        int g = idx >> 9, k = idx & (F_-1);
        stk[g][0][k] = inputStacks[(size_t)(b0+g)*F_ + k];
    }
    for (int idx = t; idx < FB_G*H_; idx += 1024) hh[idx>>10][idx&(H_-1)] = 0.f;
    int sp[FB_G], bc[FB_G], sc[FB_G];
#pragma unroll
    for (int g = 0; g < FB_G; ++g) { sp[g]=1; bc[g]=0; sc[g]=0; }
    __syncthreads();
    for (int step = 0; step < L_; ++step) {
        int op[FB_G], ti[FB_G], ri[FB_G]; bool a1=false,a2=false,a0=false;
#pragma unroll
        for (int g = 0; g < FB_G; ++g) {
            op[g] = ops[(size_t)(b0+g)*L_ + (L_-1-step)];
            int tt = sp[g]-1; tt = tt<0?0:(tt>STK_-1?STK_-1:tt); ti[g]=tt;
            int rr = sp[g]; ri[g] = rr>STK_-1?STK_-1:rr;
            a1 |= (op[g]==1); a2 |= (op[g]==2); a0 |= (op[g]==0);
        }
        const float *x0=stk[0][ti[0]], *x1=stk[1][ti[1]], *x2=stk[2][ti[2]], *x3=stk[3][ti[3]];
        if (a1) {
            float r0,r1,r2,r3; fdot4(Wd+(size_t)t*F_, x0,x1,x2,x3, F_/4, r0,r1,r2,r3);
            float bb = bd[t];
            if (op[0]==1) hh[0][t]=tanhf(r0+bb); if (op[1]==1) hh[1][t]=tanhf(r1+bb);
            if (op[2]==1) hh[2][t]=tanhf(r2+bb); if (op[3]==1) hh[3][t]=tanhf(r3+bb);
        }
        if (a2) {
            float r0,r1,r2,r3; fdot4(Wsd+(size_t)t*F_, x0,x1,x2,x3, F_/4, r0,r1,r2,r3);
            float bb = bsd[t];
            if (op[0]==2) hh[0][t]=tanhf(r0+bb); if (op[1]==2) hh[1][t]=tanhf(r1+bb);
            if (op[2]==2) hh[2][t]=tanhf(r2+bb); if (op[3]==2) hh[3][t]=tanhf(r3+bb);
        }
        if (a0 && t < FB_G*BOX_) {
            int g = t / BOX_, cc = t - g*BOX_;
            if (op[g]==0) {
                float acc = fdot1(Wbox+(size_t)cc*F_, stk[g][ti[g]], F_/4);
                boxtmp[g][bc[g]][cc] = tanhf(acc + bbox[cc]);
            }
        }
        __syncthreads();
        if (a1) {
            if (t < F_) {
                float r0,r1,r2,r3; fdot4(Wl+(size_t)t*H_, hh[0],hh[1],hh[2],hh[3], H_/4, r0,r1,r2,r3);
                float bb = bl[t];
                if (op[0]==1) stk[0][ti[0]][t]=tanhf(r0+bb); if (op[1]==1) stk[1][ti[1]][t]=tanhf(r1+bb);
                if (op[2]==1) stk[2][ti[2]][t]=tanhf(r2+bb); if (op[3]==1) stk[3][ti[3]][t]=tanhf(r3+bb);
            } else {
                int m = t - F_;
                float r0,r1,r2,r3; fdot4(Wr+(size_t)m*H_, hh[0],hh[1],hh[2],hh[3], H_/4, r0,r1,r2,r3);
                float bb = br[m];
                if (op[0]==1) stk[0][ri[0]][m]=tanhf(r0+bb); if (op[1]==1) stk[1][ri[1]][m]=tanhf(r1+bb);
                if (op[2]==1) stk[2][ri[2]][m]=tanhf(r2+bb); if (op[3]==1) stk[3][ri[3]][m]=tanhf(r3+bb);
            }
        }
        if (a2) {
            if (t < F_) {
                float r0,r1,r2,r3; fdot4(Wsf+(size_t)t*H_, hh[0],hh[1],hh[2],hh[3], H_/4, r0,r1,r2,r3);
                float bb = bsf[t];
                if (op[0]==2) stk[0][ti[0]][t]=tanhf(r0+bb); if (op[1]==2) stk[1][ti[1]][t]=tanhf(r1+bb);
                if (op[2]==2) stk[2][ti[2]][t]=tanhf(r2+bb); if (op[3]==2) stk[3][ti[3]][t]=tanhf(r3+bb);
            } else if (t < F_ + FB_G*S_) {
                int idx = t - F_, g = idx >> 3, cc = idx & 7;
                if (op[g]==2) {
                    float acc = fdot1(Wss+(size_t)cc*H_, hh[g], H_/4);
                    symtmp[g][sc[g]][cc] = tanhf(acc + bss[cc]);
                }
            }
        }
        __syncthreads();
#pragma unroll
        for (int g = 0; g < FB_G; ++g) {
            if (op[g]==1) sp[g]++;
            else if (op[g]==2) sc[g]++;
            else { bc[g]++; sp[g]--; }
        }
    }
#pragma unroll
    for (int g = 0; g < FB_G; ++g) {
        int b = b0 + g;
        float* ob = out + (size_t)b * MAXB_ * BOX_;
        for (int idx = t; idx < MAXB_*BOX_; idx += 1024) {
            int jj = idx / BOX_, cc = idx - jj*BOX_;
            int e = bc[g] - 1 - jj;
            ob[idx] = (e >= 0) ? boxtmp[g][e][cc] : 0.f;
        }
        float* os = out + (size_t)B_*MAXB_*BOX_ + (size_t)b * MAXSY_ * S_;
        for (int idx = t; idx < MAXSY_*S_; idx += 1024) {
            int jj = idx >> 3, cc = idx & 7;
            int e = sc[g] - 1 - jj;
            os[idx] = (e >= 0) ? symtmp[g][e][cc] : 0.f;
        }
    }
}

// ---------------- launcher ----------------
extern "C" void kernel_launch(void* const* d_in, const int* in_sizes, int n_in,
                              void* d_out, int out_size, void* d_ws, size_t ws_size,
                              hipStream_t stream) {
    (void)in_sizes; (void)n_in;
    const float* X    = (const float*)d_in[0];
    const int*   ops  = (const int*)d_in[1];
    const float* Wd   = (const float*)d_in[2];  const float* bd   = (const float*)d_in[3];
    const float* Wl   = (const float*)d_in[4];  const float* bl   = (const float*)d_in[5];
    const float* Wr   = (const float*)d_in[6];  const float* br   = (const float*)d_in[7];
    const float* Wsd  = (const float*)d_in[8];  const float* bsd  = (const float*)d_in[9];
    const float* Wsf  = (const float*)d_in[10]; const float* bsf  = (const float*)d_in[11];
    const float* Wss  = (const float*)d_in[12]; const float* bss  = (const float*)d_in[13];
    const float* Wbox = (const float*)d_in[14]; const float* bbox = (const float*)d_in[15];
    float* out = (float*)d_out;

    if (ws_size < WS_NEED) {
        grass_fallback<<<dim3(B_/FB_G), dim3(1024), 0, stream>>>(
            X, ops, Wd, bd, Wl, bl, Wr, br, Wsd, bsd, Wsf, bsf, Wss, bss, Wbox, bbox, out);
        return;
    }
    char* ws = (char*)d_ws;
    hipMemsetAsync(d_out, 0, (size_t)out_size * sizeof(float), stream);  // zero-pad slots
    hipMemsetAsync(ws, 0, 4096, stream);                                 // barrier counters
    grass_prep<<<dim3(512), dim3(256), 0, stream>>>(X, Wd, Wl, Wr, Wsd, Wsf, Wss, Wbox, ws);
    grass_main<<<dim3(256), dim3(256), 0, stream>>>(ops, bd, bl, br, bsd, bsf, bss, bbox, ws, out);
}